// Round 18
// baseline (36.104 us; speedup 1.0000x reference)
//
#include <hip/hip_runtime.h>
#include <math.h>

// ConvCaps EM-routing, MI355X — single-wave-per-group EM: zero LDS, zero
// barriers, all cross-lane traffic on full-rate VALU (DPP ror + permlane swaps).
//
// Algebra: vv[n,ci,co,k] = Sv(n,ci,co>>1) * Wsum(sp=n%36,ci,co,k&3), so EM
// runs on a 32x32x4 table. Lane=(h,o): h=lane>>5 owns c=h*16..h*16+15,
// o=lane&31. c-reduce = 16-reg tree + 1 permlane32_swap. Softmax over o =
// DPP rotation-allreduce within 16-rows + permlane16_swap (row0<->row1).

#define EPSF 1e-8f

typedef float f2 __attribute__((ext_vector_type(2)));
typedef unsigned u32x2 __attribute__((ext_vector_type(2)));

__device__ __forceinline__ float rcpf(float x) { return __builtin_amdgcn_rcpf(x); }

template <int CTRL>
__device__ __forceinline__ float dpp_mov(float x) {
    return __int_as_float(__builtin_amdgcn_update_dpp(
        0, __float_as_int(x), CTRL, 0xF, 0xF, true));
}

// sum/max over this lane's 16-lane DPP row (rotation allreduce)
__device__ __forceinline__ float row_sum16(float x) {
    x += dpp_mov<0x121>(x);   // row_ror:1
    x += dpp_mov<0x122>(x);   // row_ror:2
    x += dpp_mov<0x124>(x);   // row_ror:4
    x += dpp_mov<0x128>(x);   // row_ror:8
    return x;
}
__device__ __forceinline__ float row_max16(float x) {
    x = fmaxf(x, dpp_mov<0x121>(x));
    x = fmaxf(x, dpp_mov<0x122>(x));
    x = fmaxf(x, dpp_mov<0x124>(x));
    x = fmaxf(x, dpp_mov<0x128>(x));
    return x;
}
// combine with adjacent 16-row (lanes l <-> l^16)
__device__ __forceinline__ float pl16_sum(float x) {
    unsigned u = __float_as_uint(x);
    u32x2 p = __builtin_amdgcn_permlane16_swap(u, u, false, false);
    return __uint_as_float(p.x) + __uint_as_float(p.y);
}
__device__ __forceinline__ float pl16_max(float x) {
    unsigned u = __float_as_uint(x);
    u32x2 p = __builtin_amdgcn_permlane16_swap(u, u, false, false);
    return fmaxf(__uint_as_float(p.x), __uint_as_float(p.y));
}
// combine with other 32-half (lanes l <-> l^32)
__device__ __forceinline__ float pl32_sum(float x) {
    unsigned u = __float_as_uint(x);
    u32x2 p = __builtin_amdgcn_permlane32_swap(u, u, false, false);
    return __uint_as_float(p.x) + __uint_as_float(p.y);
}

// ---- pre: box-filtered channel sums (S,A) + Wsum[36][32][32][4] (R7) ----
__global__ __launch_bounds__(256) void pre_kernel(
        const float* __restrict__ x, const float* __restrict__ a,
        const float* __restrict__ w,
        float* __restrict__ S, float* __restrict__ A, float* __restrict__ Wsum) {
    int bid = blockIdx.x;
    if (bid < 1088) {
        __shared__ float plane[6272];
        __shared__ float bsum[196];
        const int t = threadIdx.x;
        const float* src = (bid < 1024) ? (x + (size_t)bid * 6272)
                                        : (a + (size_t)(bid - 1024) * 6272);
        for (int k = t; k < 1568; k += 256)
            *(float4*)&plane[k * 4] = *(const float4*)(src + k * 4);
        __syncthreads();
        if (t < 196) {
            float s = 0.f;
#pragma unroll
            for (int c = 0; c < 32; ++c) s += plane[c * 196 + t];
            bsum[t] = s;
        }
        __syncthreads();
        if (t < 36) {
            int oy = t / 6, ox = t - oy * 6;
            const float* q = &bsum[oy * 28 + ox * 2];
            float s = (q[0] + q[1] + q[2]) + (q[14] + q[15] + q[16])
                    + (q[28] + q[29] + q[30]);
            s *= (1.0f / 9.0f);
            if (bid < 1024) S[bid * 36 + t] = s;
            else            A[(bid - 1024) * 36 + t] = s;
        }
    } else {
        int wi = (bid - 1088) * 256 + threadIdx.x;   // 147456 Wsum entries
        int sp = wi >> 12;
        int rr = wi & 4095;
        int ci = rr >> 7, co = (rr >> 2) & 31, j = rr & 3;
        int B = sp * 32 + ci;
        int cc = B / 36;
        int rem = B - cc * 36;
        int wbase = cc * 18432 + (rem / 6) * 3072 + (rem % 6) * 512 + co * 16 + j;
        Wsum[wi] = w[wbase] + w[wbase + 4] + w[wbase + 8] + w[wbase + 12];
    }
}

// ---- EM: 4 independent single-wave groups per 256-thread block ----
__global__ __launch_bounds__(256, 3) void em_kernel(
        const float* __restrict__ bu, const float* __restrict__ ba,
        const float* __restrict__ S, const float* __restrict__ A,
        const float* __restrict__ Wsum, float* __restrict__ out) {
    const int t = threadIdx.x;
    const int g = t >> 6;
    const int lane = t & 63;
    const int h = lane >> 5;            // c-half
    const int o = lane & 31;            // owned output capsule
    const int n = blockIdx.x * 4 + g;
    const int bq = n / 36;
    const int sp = n - bq * 36;

    // ---- setup: direct gathers (S/A/Wsum L2-hot), no LDS, no barrier ----
    const int hc = o >> 1;
    f2 V2[16][2];
    float avr[16], r[16];
    const float* Wn = Wsum + sp * 4096;
#pragma unroll
    for (int cl = 0; cl < 16; ++cl) {
        int c = h * 16 + cl;
        int B = sp * 32 + c;
        int cc = B / 36;
        int rem = B - cc * 36;
        int off = cc * 576 + (rem / 6) * 96 + (rem % 6) * 16 + hc;
        int hi = off / 1152;
        int lo = off - hi * 1152;
        float sv = S[(bq * 16 + hi) * 36 + lo % 36];
        float4 w4 = *(const float4*)(Wn + c * 128 + o * 4);
        V2[cl][0] = (f2){sv * w4.x, sv * w4.y};
        V2[cl][1] = (f2){sv * w4.z, sv * w4.w};
        avr[cl] = A[bq * 36 + (32 * sp + c) % 36];
        r[cl] = 0.03125f;
    }
    const float bu16 = 16.0f * bu[o];
    const float ba_o = ba[o];
    f2 mu2[2], q2[2];
    float aout = 0.f;
    const float lambdas[3] = {5.0e-4f, 9.75e-4f, 1.42625e-3f};

    for (int it = 0; it < 3; ++it) {
        // ---- pass 1: rp, rs, mu (16-reg tree + one permlane32_swap) ----
        float rp[16];
#pragma unroll
        for (int cl = 0; cl < 16; ++cl) rp[cl] = r[cl] * avr[cl] + EPSF;
        float rs;
        {
            float t0 = (rp[0] + rp[1]) + (rp[2] + rp[3]);
            float t1 = (rp[4] + rp[5]) + (rp[6] + rp[7]);
            float t2 = (rp[8] + rp[9]) + (rp[10] + rp[11]);
            float t3 = (rp[12] + rp[13]) + (rp[14] + rp[15]);
            rs = pl32_sum((t0 + t1) + (t2 + t3));
        }
        float rinv = rcpf(rs);
#pragma unroll
        for (int p = 0; p < 2; ++p) {
            f2 a0 = {0.f, 0.f}, a1 = {0.f, 0.f}, a2 = {0.f, 0.f}, a3 = {0.f, 0.f};
#pragma unroll
            for (int cl = 0; cl < 16; cl += 4) {
                a0 += rp[cl] * V2[cl][p];
                a1 += rp[cl + 1] * V2[cl + 1][p];
                a2 += rp[cl + 2] * V2[cl + 2][p];
                a3 += rp[cl + 3] * V2[cl + 3][p];
            }
            f2 m = (a0 + a1) + (a2 + a3);
            m.x = pl32_sum(m.x);
            m.y = pl32_sum(m.y);
            mu2[p] = m * rinv;
        }
        // ---- pass 2: sig (non-negative), single fused log ----
        float L;
        {
            f2 sgv[2];
#pragma unroll
            for (int p = 0; p < 2; ++p) {
                f2 a0 = {0.f, 0.f}, a1 = {0.f, 0.f}, a2 = {0.f, 0.f}, a3 = {0.f, 0.f};
#pragma unroll
                for (int cl = 0; cl < 16; cl += 4) {
                    f2 d0 = V2[cl][p] - mu2[p];
                    f2 d1 = V2[cl + 1][p] - mu2[p];
                    f2 d2 = V2[cl + 2][p] - mu2[p];
                    f2 d3 = V2[cl + 3][p] - mu2[p];
                    a0 += (d0 * d0) * rp[cl];
                    a1 += (d1 * d1) * rp[cl + 1];
                    a2 += (d2 * d2) * rp[cl + 2];
                    a3 += (d3 * d3) * rp[cl + 3];
                }
                f2 sg = (a0 + a1) + (a2 + a3);
                sg.x = pl32_sum(sg.x);
                sg.y = pl32_sum(sg.y);
                sgv[p] = sg * rinv + EPSF;
                q2[p] = (f2){2.0f * rcpf(sgv[p].x), 2.0f * rcpf(sgv[p].y)};
            }
            L = __logf((sgv[0].x * sgv[0].y) * (sgv[1].x * sgv[1].y));
        }
        float cost = (bu16 + 2.0f * L) * rs;
        float z = lambdas[it] * (ba_o - cost);

        if (it < 2) {
            // logits in REGISTERS; log-sigmoid identity
            float la = -__logf(1.0f + __expf(-z));
            float T = la - 2.0f * L;
            float lg[16];
#pragma unroll
            for (int cl = 0; cl < 16; ++cl) {
                f2 d0 = V2[cl][0] - mu2[0];
                f2 d1 = V2[cl][1] - mu2[1];
                f2 s2 = (d0 * d0) * q2[0] + (d1 * d1) * q2[1];
                lg[cl] = T - (s2.x + s2.y);
            }
            // softmax over the 32 o-lanes, fully in-register (16 indep chains)
#pragma unroll
            for (int cl = 0; cl < 16; ++cl) {
                float m = pl16_max(row_max16(lg[cl]));
                float e = __expf(lg[cl] - m);
                float ssum = pl16_sum(row_sum16(e));
                r[cl] = e * rcpf(ssum);
            }
        } else {
            aout = rcpf(1.0f + __expf(-z));
        }
    }

    // outputs: mu expanded to 16 k (k>>2 drops out); both h hold identical mu —
    // each writes half of the 16-k row (2 float4 each).
    float4 val = {mu2[0].x, mu2[0].y, mu2[1].x, mu2[1].y};
    float4* po = (float4*)(out + n * 512 + o * 16);
    po[2 * h] = val;
    po[2 * h + 1] = val;
    if (h == 0) out[1179648 + n * 32 + o] = aout;
}

extern "C" void kernel_launch(void* const* d_in, const int* in_sizes, int n_in,
                              void* d_out, int out_size, void* d_ws, size_t ws_size,
                              hipStream_t stream) {
    const float* x = (const float*)d_in[0];
    const float* a = (const float*)d_in[1];
    const float* w = (const float*)d_in[2];
    const float* bu = (const float*)d_in[3];
    const float* ba = (const float*)d_in[4];
    float* out = (float*)d_out;

    float* S    = (float*)d_ws;          // 36864
    float* A    = S + 36864;             // 2304
    float* Wsum = A + 2304;              // 147456

    pre_kernel<<<1088 + 576, 256, 0, stream>>>(x, a, w, S, A, Wsum);
    em_kernel<<<576, 256, 0, stream>>>(bu, ba, S, A, Wsum, out);
}

// Round 19
// 21.335 us; speedup vs baseline: 1.6923x; 1.6923x over previous
//
#include <hip/hip_runtime.h>
#include <math.h>

// ConvCaps EM-routing, MI355X — R16 (best) + precomputed gather-index tables
// (kills em's div/mod setup chains).
//
// Algebra: vv[n,ci,co,k] = Sv(n,ci,co>>1) * Wsum(sp=n%36,ci,co,k&3), so EM
// runs on a 32x32x4 table. EM block = 128 threads (2 waves) per group.
// Wave wv owns o = wv*16+(lane&15); cq = lane>>4 owns c = cq*8..cq*8+7.

#define EPSF 1e-8f

typedef float f2 __attribute__((ext_vector_type(2)));
typedef unsigned u32x2 __attribute__((ext_vector_type(2)));

__device__ __forceinline__ float rcpf(float x) { return __builtin_amdgcn_rcpf(x); }

// sum over the 4 lanes {l, l^16, l^32, l^48}; result in all 4 lanes.
__device__ __forceinline__ float reduce4(float x) {
#if __has_builtin(__builtin_amdgcn_permlane16_swap) && __has_builtin(__builtin_amdgcn_permlane32_swap)
    unsigned xu = __float_as_uint(x);
    u32x2 p = __builtin_amdgcn_permlane16_swap(xu, xu, false, false);
    float s = __uint_as_float(p.x) + __uint_as_float(p.y);
    unsigned su = __float_as_uint(s);
    u32x2 q = __builtin_amdgcn_permlane32_swap(su, su, false, false);
    return __uint_as_float(q.x) + __uint_as_float(q.y);
#else
    x += __shfl_xor(x, 16);
    x += __shfl_xor(x, 32);
    return x;
#endif
}

// intra-quad lane swaps via DPP (full-rate VALU, no DS pipe)
__device__ __forceinline__ float dpp_xor1(float x) {
    return __int_as_float(__builtin_amdgcn_update_dpp(
        0, __float_as_int(x), 0xB1, 0xF, 0xF, true));   // quad_perm [1,0,3,2]
}
__device__ __forceinline__ float dpp_xor2(float x) {
    return __int_as_float(__builtin_amdgcn_update_dpp(
        0, __float_as_int(x), 0x4E, 0xF, 0xF, true));   // quad_perm [2,3,0,1]
}

// ---- pre: box-filtered channel sums (S,A) + Wsum + gather-index tables ----
__global__ __launch_bounds__(256) void pre_kernel(
        const float* __restrict__ x, const float* __restrict__ a,
        const float* __restrict__ w,
        float* __restrict__ S, float* __restrict__ A, float* __restrict__ Wsum,
        unsigned short* __restrict__ sidx, unsigned char* __restrict__ aidx) {
    int bid = blockIdx.x;
    if (bid < 1088) {
        __shared__ float plane[6272];
        __shared__ float bsum[196];
        const int t = threadIdx.x;
        const float* src = (bid < 1024) ? (x + (size_t)bid * 6272)
                                        : (a + (size_t)(bid - 1024) * 6272);
        for (int k = t; k < 1568; k += 256)
            *(float4*)&plane[k * 4] = *(const float4*)(src + k * 4);
        __syncthreads();
        if (t < 196) {
            float s = 0.f;
#pragma unroll
            for (int c = 0; c < 32; ++c) s += plane[c * 196 + t];
            bsum[t] = s;
        }
        __syncthreads();
        if (t < 36) {
            int oy = t / 6, ox = t - oy * 6;
            const float* q = &bsum[oy * 28 + ox * 2];
            float s = (q[0] + q[1] + q[2]) + (q[14] + q[15] + q[16])
                    + (q[28] + q[29] + q[30]);
            s *= (1.0f / 9.0f);
            if (bid < 1024) S[bid * 36 + t] = s;
            else            A[(bid - 1024) * 36 + t] = s;
        }
    } else if (bid < 1664) {
        int wi = (bid - 1088) * 256 + threadIdx.x;   // 147456 Wsum entries
        int sp = wi >> 12;
        int rr = wi & 4095;
        int ci = rr >> 7, co = (rr >> 2) & 31, j = rr & 3;
        int B = sp * 32 + ci;
        int cc = B / 36;
        int rem = B - cc * 36;
        int wbase = cc * 18432 + (rem / 6) * 3072 + (rem % 6) * 512 + co * 16 + j;
        Wsum[wi] = w[wbase] + w[wbase + 4] + w[wbase + 8] + w[wbase + 12];
    } else {
        int ti = (bid - 1664) * 256 + threadIdx.x;
        if (ti < 18432) {                 // sidx[sp][c][hc]
            int sp = ti >> 9;
            int r2 = ti & 511;
            int c = r2 >> 4, hcv = r2 & 15;
            int B = sp * 32 + c;
            int cc = B / 36;
            int rem = B - cc * 36;
            int off = cc * 576 + (rem / 6) * 96 + (rem % 6) * 16 + hcv;
            int hi = off / 1152;
            int lo = off - hi * 1152;
            sidx[ti] = (unsigned short)(hi * 36 + lo % 36);
        } else if (ti < 18432 + 1152) {   // aidx[sp][c] = (sp*32+c)%36
            int k = ti - 18432;
            aidx[k] = (unsigned char)(k % 36);
        }
    }
}

// ---- EM: one 128-thread block (2 waves) per routing group ----
__global__ __launch_bounds__(128, 4) void em_kernel(
        const float* __restrict__ bu, const float* __restrict__ ba,
        const float* __restrict__ S, const float* __restrict__ A,
        const float* __restrict__ Wsum,
        const unsigned short* __restrict__ sidx,
        const unsigned char* __restrict__ aidx,
        float* __restrict__ out) {
    __shared__ float lgb[33 * 32];      // [c][o], stride 33 (only LDS use)

    const int t = threadIdx.x;
    const int w = t >> 6;
    const int lane = t & 63;
    const int o = w * 16 + (lane & 15); // owned output capsule
    const int cq = lane >> 4;           // c-quarter (0..3)
    const int c0 = cq * 8;
    const int n = blockIdx.x;
    const int bq = n / 36;
    const int sp = n - bq * 36;

    // ---- setup: table-driven gathers (all L2-hot), no staging barrier ----
    const int hc = o >> 1;
    const unsigned short* sid = sidx + sp * 512;
    const unsigned char* aid = aidx + sp * 32;
    const float* Sb = S + bq * 576;
    const float* Ab = A + bq * 36;
    f2 V2[8][2];
    float avr[8], r[8];
    const float* Wn = Wsum + sp * 4096;
#pragma unroll
    for (int cl = 0; cl < 8; ++cl) {
        int c = c0 + cl;
        float sv = Sb[sid[c * 16 + hc]];
        float4 w4 = *(const float4*)(Wn + c * 128 + o * 4);
        V2[cl][0] = (f2){sv * w4.x, sv * w4.y};
        V2[cl][1] = (f2){sv * w4.z, sv * w4.w};
        avr[cl] = Ab[aid[c]];
        r[cl] = 0.03125f;
    }
    const float bu16 = 16.0f * bu[o];
    const float ba_o = ba[o];
    f2 mu2[2], q2[2];
    float aout = 0.f;
    const float lambdas[3] = {5.0e-4f, 9.75e-4f, 1.42625e-3f};

    for (int it = 0; it < 3; ++it) {
        // ---- pass 1: rp, rs, mu (4-lane reduce via permlane swaps) ----
        float rp[8];
#pragma unroll
        for (int cl = 0; cl < 8; ++cl) rp[cl] = r[cl] * avr[cl] + EPSF;
        float rs = ((rp[0] + rp[1]) + (rp[2] + rp[3]))
                 + ((rp[4] + rp[5]) + (rp[6] + rp[7]));
        rs = reduce4(rs);
        float rinv = rcpf(rs);
#pragma unroll
        for (int p = 0; p < 2; ++p) {
            f2 a0 = {0.f, 0.f}, a1 = {0.f, 0.f};
#pragma unroll
            for (int cl = 0; cl < 8; cl += 2) {
                a0 += rp[cl] * V2[cl][p];
                a1 += rp[cl + 1] * V2[cl + 1][p];
            }
            f2 m = a0 + a1;
            m.x = reduce4(m.x);
            m.y = reduce4(m.y);
            mu2[p] = m * rinv;
        }
        // ---- pass 2: sig (non-negative), single fused log ----
        float L;
        {
            f2 sgv[2];
#pragma unroll
            for (int p = 0; p < 2; ++p) {
                f2 a0 = {0.f, 0.f}, a1 = {0.f, 0.f};
#pragma unroll
                for (int cl = 0; cl < 8; cl += 2) {
                    f2 d0 = V2[cl][p] - mu2[p];
                    f2 d1 = V2[cl + 1][p] - mu2[p];
                    a0 += (d0 * d0) * rp[cl];
                    a1 += (d1 * d1) * rp[cl + 1];
                }
                f2 sg = a0 + a1;
                sg.x = reduce4(sg.x);
                sg.y = reduce4(sg.y);
                sgv[p] = sg * rinv + EPSF;
                q2[p] = (f2){2.0f * rcpf(sgv[p].x), 2.0f * rcpf(sgv[p].y)};
            }
            L = __logf((sgv[0].x * sgv[0].y) * (sgv[1].x * sgv[1].y));
        }
        float cost = (bu16 + 2.0f * L) * rs;
        float z = lambdas[it] * (ba_o - cost);

        if (it < 2) {
            // log-sigmoid identity: log(aout) = -log(1 + e^-z)
            float la = -__logf(1.0f + __expf(-z));
            float T = la - 2.0f * L;
#pragma unroll
            for (int cl = 0; cl < 8; ++cl) {
                f2 d0 = V2[cl][0] - mu2[0];
                f2 d1 = V2[cl][1] - mu2[1];
                f2 s2 = (d0 * d0) * q2[0] + (d1 * d1) * q2[1];
                lgb[(c0 + cl) * 33 + o] = T - (s2.x + s2.y);
            }
            __syncthreads();
            // transposed softmax: 128 lanes, lane = (c-row, quarter of o-row)
            {
                int cT = t >> 2, q = t & 3;
                float* rowp = &lgb[cT * 33 + q * 8];
                float4 u0 = *(float4*)(rowp);
                float4 u1 = *(float4*)(rowp + 4);
                float m0 = fmaxf(fmaxf(u0.x, u0.y), fmaxf(u0.z, u0.w));
                float m1 = fmaxf(fmaxf(u1.x, u1.y), fmaxf(u1.z, u1.w));
                float m = fmaxf(m0, m1);
                m = fmaxf(m, dpp_xor1(m));
                m = fmaxf(m, dpp_xor2(m));
                u0.x = __expf(u0.x - m); u0.y = __expf(u0.y - m);
                u0.z = __expf(u0.z - m); u0.w = __expf(u0.w - m);
                u1.x = __expf(u1.x - m); u1.y = __expf(u1.y - m);
                u1.z = __expf(u1.z - m); u1.w = __expf(u1.w - m);
                float s0 = (u0.x + u0.y) + (u0.z + u0.w);
                float s1 = (u1.x + u1.y) + (u1.z + u1.w);
                float ssum = s0 + s1;
                ssum += dpp_xor1(ssum);
                ssum += dpp_xor2(ssum);
                float inv = rcpf(ssum);
                u0.x *= inv; u0.y *= inv; u0.z *= inv; u0.w *= inv;
                u1.x *= inv; u1.y *= inv; u1.z *= inv; u1.w *= inv;
                *(float4*)(rowp)     = u0;
                *(float4*)(rowp + 4) = u1;
            }
            __syncthreads();
#pragma unroll
            for (int cl = 0; cl < 8; ++cl)
                r[cl] = lgb[(c0 + cl) * 33 + o];
        } else {
            aout = rcpf(1.0f + __expf(-z));
        }
    }

    // outputs: mu expanded to 16 k (k>>2 drops out); 4 cq-lanes hold identical
    // mu for their o — each writes one float4 quarter of the 16-k row.
    float4 val = {mu2[0].x, mu2[0].y, mu2[1].x, mu2[1].y};
    float4* po = (float4*)(out + n * 512 + o * 16);
    po[cq] = val;
    if (cq == 0) out[1179648 + n * 32 + o] = aout;
}

extern "C" void kernel_launch(void* const* d_in, const int* in_sizes, int n_in,
                              void* d_out, int out_size, void* d_ws, size_t ws_size,
                              hipStream_t stream) {
    const float* x = (const float*)d_in[0];
    const float* a = (const float*)d_in[1];
    const float* w = (const float*)d_in[2];
    const float* bu = (const float*)d_in[3];
    const float* ba = (const float*)d_in[4];
    float* out = (float*)d_out;

    float* S    = (float*)d_ws;                       // 36864 f
    float* A    = S + 36864;                          // 2304 f
    float* Wsum = A + 2304;                           // 147456 f
    unsigned short* sidx = (unsigned short*)(Wsum + 147456);  // 18432 u16
    unsigned char*  aidx = (unsigned char*)(sidx + 18432);    // 1152 u8

    pre_kernel<<<1088 + 576 + 77, 256, 0, stream>>>(x, a, w, S, A, Wsum, sidx, aidx);
    em_kernel<<<2304, 128, 0, stream>>>(bu, ba, S, A, Wsum, sidx, aidx, out);
}

// Round 21
// 20.813 us; speedup vs baseline: 1.7347x; 1.0251x over previous
//
#include <hip/hip_runtime.h>
#include <math.h>

// ConvCaps EM-routing, MI355X — R19 + vectorized index loads (ushort8/uchar8)
// + base-2 transcendental domain via raw HW builtins (v_exp_f32 = 2^x,
// v_log_f32 = log2 x — no ln2 fixup muls).
//
// Algebra: vv[n,ci,co,k] = Sv(n,ci,co>>1) * Wsum(sp=n%36,ci,co,k&3), so EM
// runs on a 32x32x4 table. EM block = 128 threads (2 waves) per group.
// Wave wv owns o = wv*16+(lane&15); cq = lane>>4 owns c = cq*8..cq*8+7.

#define EPSF 1e-8f
#define LOG2E_F 1.44269504089f
#define LN2X2_F 1.38629436112f   // 2*ln2

typedef float f2 __attribute__((ext_vector_type(2)));
typedef unsigned u32x2 __attribute__((ext_vector_type(2)));
typedef unsigned short ushort8v __attribute__((ext_vector_type(8)));
typedef unsigned char uchar8v __attribute__((ext_vector_type(8)));

__device__ __forceinline__ float rcpf(float x) { return __builtin_amdgcn_rcpf(x); }
__device__ __forceinline__ float exp2f_hw(float x) { return __builtin_amdgcn_exp2f(x); }
__device__ __forceinline__ float log2f_hw(float x) { return __builtin_amdgcn_logf(x); }

// sum over the 4 lanes {l, l^16, l^32, l^48}; result in all 4 lanes.
__device__ __forceinline__ float reduce4(float x) {
#if __has_builtin(__builtin_amdgcn_permlane16_swap) && __has_builtin(__builtin_amdgcn_permlane32_swap)
    unsigned xu = __float_as_uint(x);
    u32x2 p = __builtin_amdgcn_permlane16_swap(xu, xu, false, false);
    float s = __uint_as_float(p.x) + __uint_as_float(p.y);
    unsigned su = __float_as_uint(s);
    u32x2 q = __builtin_amdgcn_permlane32_swap(su, su, false, false);
    return __uint_as_float(q.x) + __uint_as_float(q.y);
#else
    x += __shfl_xor(x, 16);
    x += __shfl_xor(x, 32);
    return x;
#endif
}

// intra-quad lane swaps via DPP (full-rate VALU, no DS pipe)
__device__ __forceinline__ float dpp_xor1(float x) {
    return __int_as_float(__builtin_amdgcn_update_dpp(
        0, __float_as_int(x), 0xB1, 0xF, 0xF, true));   // quad_perm [1,0,3,2]
}
__device__ __forceinline__ float dpp_xor2(float x) {
    return __int_as_float(__builtin_amdgcn_update_dpp(
        0, __float_as_int(x), 0x4E, 0xF, 0xF, true));   // quad_perm [2,3,0,1]
}

// ---- pre: box-filtered channel sums (S,A) + Wsum + gather-index tables ----
__global__ __launch_bounds__(256) void pre_kernel(
        const float* __restrict__ x, const float* __restrict__ a,
        const float* __restrict__ w,
        float* __restrict__ S, float* __restrict__ A, float* __restrict__ Wsum,
        unsigned short* __restrict__ sidx, unsigned char* __restrict__ aidx) {
    int bid = blockIdx.x;
    if (bid < 1088) {
        __shared__ float plane[6272];
        __shared__ float bsum[196];
        const int t = threadIdx.x;
        const float* src = (bid < 1024) ? (x + (size_t)bid * 6272)
                                        : (a + (size_t)(bid - 1024) * 6272);
        for (int k = t; k < 1568; k += 256)
            *(float4*)&plane[k * 4] = *(const float4*)(src + k * 4);
        __syncthreads();
        if (t < 196) {
            float s = 0.f;
#pragma unroll
            for (int c = 0; c < 32; ++c) s += plane[c * 196 + t];
            bsum[t] = s;
        }
        __syncthreads();
        if (t < 36) {
            int oy = t / 6, ox = t - oy * 6;
            const float* q = &bsum[oy * 28 + ox * 2];
            float s = (q[0] + q[1] + q[2]) + (q[14] + q[15] + q[16])
                    + (q[28] + q[29] + q[30]);
            s *= (1.0f / 9.0f);
            if (bid < 1024) S[bid * 36 + t] = s;
            else            A[(bid - 1024) * 36 + t] = s;
        }
    } else if (bid < 1664) {
        int wi = (bid - 1088) * 256 + threadIdx.x;   // 147456 Wsum entries
        int sp = wi >> 12;
        int rr = wi & 4095;
        int ci = rr >> 7, co = (rr >> 2) & 31, j = rr & 3;
        int B = sp * 32 + ci;
        int cc = B / 36;
        int rem = B - cc * 36;
        int wbase = cc * 18432 + (rem / 6) * 3072 + (rem % 6) * 512 + co * 16 + j;
        Wsum[wi] = w[wbase] + w[wbase + 4] + w[wbase + 8] + w[wbase + 12];
    } else {
        int ti = (bid - 1664) * 256 + threadIdx.x;
        if (ti < 18432) {                 // sidxT[sp][hc][c]  (c contiguous)
            int sp = ti >> 9;
            int r2 = ti & 511;
            int hcv = r2 >> 5, c = r2 & 31;
            int B = sp * 32 + c;
            int cc = B / 36;
            int rem = B - cc * 36;
            int off = cc * 576 + (rem / 6) * 96 + (rem % 6) * 16 + hcv;
            int hi = off / 1152;
            int lo = off - hi * 1152;
            sidx[ti] = (unsigned short)(hi * 36 + lo % 36);
        } else if (ti < 18432 + 1152) {   // aidx[sp][c] = (sp*32+c)%36
            int k = ti - 18432;
            aidx[k] = (unsigned char)(k % 36);
        }
    }
}

// ---- EM: one 128-thread block (2 waves) per routing group ----
__global__ __launch_bounds__(128, 4) void em_kernel(
        const float* __restrict__ bu, const float* __restrict__ ba,
        const float* __restrict__ S, const float* __restrict__ A,
        const float* __restrict__ Wsum,
        const unsigned short* __restrict__ sidx,
        const unsigned char* __restrict__ aidx,
        float* __restrict__ out) {
    __shared__ float lgb[33 * 32];      // [c][o], stride 33 (only LDS use)

    const int t = threadIdx.x;
    const int w = t >> 6;
    const int lane = t & 63;
    const int o = w * 16 + (lane & 15); // owned output capsule
    const int cq = lane >> 4;           // c-quarter (0..3)
    const int c0 = cq * 8;
    const int n = blockIdx.x;
    const int bq = n / 36;
    const int sp = n - bq * 36;

    // ---- setup: vectorized index loads + table-driven gathers ----
    const int hc = o >> 1;
    const ushort8v sv8 = *(const ushort8v*)(sidx + sp * 512 + hc * 32 + c0);
    const uchar8v av8 = *(const uchar8v*)(aidx + sp * 32 + c0);
    const float* Sb = S + bq * 576;
    const float* Ab = A + bq * 36;
    f2 V2[8][2];
    float avr[8], r[8];
    const float* Wn = Wsum + sp * 4096;
#pragma unroll
    for (int cl = 0; cl < 8; ++cl) {
        int c = c0 + cl;
        float sv = Sb[sv8[cl]];
        float4 w4 = *(const float4*)(Wn + c * 128 + o * 4);
        V2[cl][0] = (f2){sv * w4.x, sv * w4.y};
        V2[cl][1] = (f2){sv * w4.z, sv * w4.w};
        avr[cl] = Ab[av8[cl]];
        r[cl] = 0.03125f;
    }
    const float bu16 = 16.0f * bu[o];
    const float ba_o = ba[o];
    f2 mu2[2], q2K[2];
    float aout = 0.f;
    const float lambdas[3] = {5.0e-4f, 9.75e-4f, 1.42625e-3f};

    for (int it = 0; it < 3; ++it) {
        // ---- pass 1: rp, rs, mu (4-lane reduce via permlane swaps) ----
        float rp[8];
#pragma unroll
        for (int cl = 0; cl < 8; ++cl) rp[cl] = r[cl] * avr[cl] + EPSF;
        float rs = ((rp[0] + rp[1]) + (rp[2] + rp[3]))
                 + ((rp[4] + rp[5]) + (rp[6] + rp[7]));
        rs = reduce4(rs);
        float rinv = rcpf(rs);
#pragma unroll
        for (int p = 0; p < 2; ++p) {
            f2 a0 = {0.f, 0.f}, a1 = {0.f, 0.f};
#pragma unroll
            for (int cl = 0; cl < 8; cl += 2) {
                a0 += rp[cl] * V2[cl][p];
                a1 += rp[cl + 1] * V2[cl + 1][p];
            }
            f2 m = a0 + a1;
            m.x = reduce4(m.x);
            m.y = reduce4(m.y);
            mu2[p] = m * rinv;
        }
        // ---- pass 2: sig (non-negative), single fused log2 ----
        float L2;   // log2(prod of 4 sigmas)
        {
            f2 sgv[2];
#pragma unroll
            for (int p = 0; p < 2; ++p) {
                f2 a0 = {0.f, 0.f}, a1 = {0.f, 0.f};
#pragma unroll
                for (int cl = 0; cl < 8; cl += 2) {
                    f2 d0 = V2[cl][p] - mu2[p];
                    f2 d1 = V2[cl + 1][p] - mu2[p];
                    a0 += (d0 * d0) * rp[cl];
                    a1 += (d1 * d1) * rp[cl + 1];
                }
                f2 sg = a0 + a1;
                sg.x = reduce4(sg.x);
                sg.y = reduce4(sg.y);
                sgv[p] = sg * rinv + EPSF;
                // fold log2e into q: q2K = (2*log2e)/sg
                q2K[p] = (f2){(2.0f * LOG2E_F) * rcpf(sgv[p].x),
                              (2.0f * LOG2E_F) * rcpf(sgv[p].y)};
            }
            L2 = log2f_hw((sgv[0].x * sgv[0].y) * (sgv[1].x * sgv[1].y));
        }
        float cost = (bu16 + LN2X2_F * L2) * rs;   // 2*L (natural) = 2*ln2*L2
        float z = lambdas[it] * (ba_o - cost);
        float e2z = exp2f_hw(-z * LOG2E_F);        // e^{-z}

        if (it < 2) {
            // base-2 log-sigmoid: la*K = -log2(1 + e^{-z})
            float laK = -log2f_hw(1.0f + e2z);
            float TK = laK - 2.0f * L2;            // logits in log2 units
#pragma unroll
            for (int cl = 0; cl < 8; ++cl) {
                f2 d0 = V2[cl][0] - mu2[0];
                f2 d1 = V2[cl][1] - mu2[1];
                f2 s2 = (d0 * d0) * q2K[0] + (d1 * d1) * q2K[1];
                lgb[(c0 + cl) * 33 + o] = TK - (s2.x + s2.y);
            }
            __syncthreads();
            // transposed softmax (base-2): 128 lanes, lane = (c-row, o-quarter)
            {
                int cT = t >> 2, q = t & 3;
                float* rowp = &lgb[cT * 33 + q * 8];
                float4 u0 = *(float4*)(rowp);
                float4 u1 = *(float4*)(rowp + 4);
                float m0 = fmaxf(fmaxf(u0.x, u0.y), fmaxf(u0.z, u0.w));
                float m1 = fmaxf(fmaxf(u1.x, u1.y), fmaxf(u1.z, u1.w));
                float m = fmaxf(m0, m1);
                m = fmaxf(m, dpp_xor1(m));
                m = fmaxf(m, dpp_xor2(m));
                u0.x = exp2f_hw(u0.x - m); u0.y = exp2f_hw(u0.y - m);
                u0.z = exp2f_hw(u0.z - m); u0.w = exp2f_hw(u0.w - m);
                u1.x = exp2f_hw(u1.x - m); u1.y = exp2f_hw(u1.y - m);
                u1.z = exp2f_hw(u1.z - m); u1.w = exp2f_hw(u1.w - m);
                float s0 = (u0.x + u0.y) + (u0.z + u0.w);
                float s1 = (u1.x + u1.y) + (u1.z + u1.w);
                float ssum = s0 + s1;
                ssum += dpp_xor1(ssum);
                ssum += dpp_xor2(ssum);
                float inv = rcpf(ssum);
                u0.x *= inv; u0.y *= inv; u0.z *= inv; u0.w *= inv;
                u1.x *= inv; u1.y *= inv; u1.z *= inv; u1.w *= inv;
                *(float4*)(rowp)     = u0;
                *(float4*)(rowp + 4) = u1;
            }
            __syncthreads();
#pragma unroll
            for (int cl = 0; cl < 8; ++cl)
                r[cl] = lgb[(c0 + cl) * 33 + o];
        } else {
            aout = rcpf(1.0f + e2z);
        }
    }

    // outputs: mu expanded to 16 k (k>>2 drops out); 4 cq-lanes hold identical
    // mu for their o — each writes one float4 quarter of the 16-k row.
    float4 val = {mu2[0].x, mu2[0].y, mu2[1].x, mu2[1].y};
    float4* po = (float4*)(out + n * 512 + o * 16);
    po[cq] = val;
    if (cq == 0) out[1179648 + n * 32 + o] = aout;
}

extern "C" void kernel_launch(void* const* d_in, const int* in_sizes, int n_in,
                              void* d_out, int out_size, void* d_ws, size_t ws_size,
                              hipStream_t stream) {
    const float* x = (const float*)d_in[0];
    const float* a = (const float*)d_in[1];
    const float* w = (const float*)d_in[2];
    const float* bu = (const float*)d_in[3];
    const float* ba = (const float*)d_in[4];
    float* out = (float*)d_out;

    float* S    = (float*)d_ws;                       // 36864 f
    float* A    = S + 36864;                          // 2304 f
    float* Wsum = A + 2304;                           // 147456 f
    unsigned short* sidx = (unsigned short*)(Wsum + 147456);  // 18432 u16
    unsigned char*  aidx = (unsigned char*)(sidx + 18432);    // 1152 u8

    pre_kernel<<<1088 + 576 + 77, 256, 0, stream>>>(x, a, w, S, A, Wsum, sidx, aidx);
    em_kernel<<<2304, 128, 0, stream>>>(bu, ba, S, A, Wsum, sidx, aidx, out);
}

// Round 22
// 20.804 us; speedup vs baseline: 1.7355x; 1.0004x over previous
//
#include <hip/hip_runtime.h>
#include <math.h>

// ConvCaps EM-routing, MI355X — R21 + one-pass m-step (shared rp·V product,
// E[V^2]-mu^2 with non-negativity clamp; 9 independent reduce4 chains).
//
// Algebra: vv[n,ci,co,k] = Sv(n,ci,co>>1) * Wsum(sp=n%36,ci,co,k&3), so EM
// runs on a 32x32x4 table. EM block = 128 threads (2 waves) per group.
// Wave wv owns o = wv*16+(lane&15); cq = lane>>4 owns c = cq*8..cq*8+7.

#define EPSF 1e-8f
#define LOG2E_F 1.44269504089f
#define LN2X2_F 1.38629436112f   // 2*ln2

typedef float f2 __attribute__((ext_vector_type(2)));
typedef unsigned u32x2 __attribute__((ext_vector_type(2)));
typedef unsigned short ushort8v __attribute__((ext_vector_type(8)));
typedef unsigned char uchar8v __attribute__((ext_vector_type(8)));

__device__ __forceinline__ float rcpf(float x) { return __builtin_amdgcn_rcpf(x); }
__device__ __forceinline__ float exp2f_hw(float x) { return __builtin_amdgcn_exp2f(x); }
__device__ __forceinline__ float log2f_hw(float x) { return __builtin_amdgcn_logf(x); }

// sum over the 4 lanes {l, l^16, l^32, l^48}; result in all 4 lanes.
__device__ __forceinline__ float reduce4(float x) {
#if __has_builtin(__builtin_amdgcn_permlane16_swap) && __has_builtin(__builtin_amdgcn_permlane32_swap)
    unsigned xu = __float_as_uint(x);
    u32x2 p = __builtin_amdgcn_permlane16_swap(xu, xu, false, false);
    float s = __uint_as_float(p.x) + __uint_as_float(p.y);
    unsigned su = __float_as_uint(s);
    u32x2 q = __builtin_amdgcn_permlane32_swap(su, su, false, false);
    return __uint_as_float(q.x) + __uint_as_float(q.y);
#else
    x += __shfl_xor(x, 16);
    x += __shfl_xor(x, 32);
    return x;
#endif
}

// intra-quad lane swaps via DPP (full-rate VALU, no DS pipe)
__device__ __forceinline__ float dpp_xor1(float x) {
    return __int_as_float(__builtin_amdgcn_update_dpp(
        0, __float_as_int(x), 0xB1, 0xF, 0xF, true));   // quad_perm [1,0,3,2]
}
__device__ __forceinline__ float dpp_xor2(float x) {
    return __int_as_float(__builtin_amdgcn_update_dpp(
        0, __float_as_int(x), 0x4E, 0xF, 0xF, true));   // quad_perm [2,3,0,1]
}

// ---- pre: box-filtered channel sums (S,A) + Wsum + gather-index tables ----
__global__ __launch_bounds__(256) void pre_kernel(
        const float* __restrict__ x, const float* __restrict__ a,
        const float* __restrict__ w,
        float* __restrict__ S, float* __restrict__ A, float* __restrict__ Wsum,
        unsigned short* __restrict__ sidx, unsigned char* __restrict__ aidx) {
    int bid = blockIdx.x;
    if (bid < 1088) {
        __shared__ float plane[6272];
        __shared__ float bsum[196];
        const int t = threadIdx.x;
        const float* src = (bid < 1024) ? (x + (size_t)bid * 6272)
                                        : (a + (size_t)(bid - 1024) * 6272);
        for (int k = t; k < 1568; k += 256)
            *(float4*)&plane[k * 4] = *(const float4*)(src + k * 4);
        __syncthreads();
        if (t < 196) {
            float s = 0.f;
#pragma unroll
            for (int c = 0; c < 32; ++c) s += plane[c * 196 + t];
            bsum[t] = s;
        }
        __syncthreads();
        if (t < 36) {
            int oy = t / 6, ox = t - oy * 6;
            const float* q = &bsum[oy * 28 + ox * 2];
            float s = (q[0] + q[1] + q[2]) + (q[14] + q[15] + q[16])
                    + (q[28] + q[29] + q[30]);
            s *= (1.0f / 9.0f);
            if (bid < 1024) S[bid * 36 + t] = s;
            else            A[(bid - 1024) * 36 + t] = s;
        }
    } else if (bid < 1664) {
        int wi = (bid - 1088) * 256 + threadIdx.x;   // 147456 Wsum entries
        int sp = wi >> 12;
        int rr = wi & 4095;
        int ci = rr >> 7, co = (rr >> 2) & 31, j = rr & 3;
        int B = sp * 32 + ci;
        int cc = B / 36;
        int rem = B - cc * 36;
        int wbase = cc * 18432 + (rem / 6) * 3072 + (rem % 6) * 512 + co * 16 + j;
        Wsum[wi] = w[wbase] + w[wbase + 4] + w[wbase + 8] + w[wbase + 12];
    } else {
        int ti = (bid - 1664) * 256 + threadIdx.x;
        if (ti < 18432) {                 // sidxT[sp][hc][c]  (c contiguous)
            int sp = ti >> 9;
            int r2 = ti & 511;
            int hcv = r2 >> 5, c = r2 & 31;
            int B = sp * 32 + c;
            int cc = B / 36;
            int rem = B - cc * 36;
            int off = cc * 576 + (rem / 6) * 96 + (rem % 6) * 16 + hcv;
            int hi = off / 1152;
            int lo = off - hi * 1152;
            sidx[ti] = (unsigned short)(hi * 36 + lo % 36);
        } else if (ti < 18432 + 1152) {   // aidx[sp][c] = (sp*32+c)%36
            int k = ti - 18432;
            aidx[k] = (unsigned char)(k % 36);
        }
    }
}

// ---- EM: one 128-thread block (2 waves) per routing group ----
__global__ __launch_bounds__(128, 4) void em_kernel(
        const float* __restrict__ bu, const float* __restrict__ ba,
        const float* __restrict__ S, const float* __restrict__ A,
        const float* __restrict__ Wsum,
        const unsigned short* __restrict__ sidx,
        const unsigned char* __restrict__ aidx,
        float* __restrict__ out) {
    __shared__ float lgb[33 * 32];      // [c][o], stride 33 (only LDS use)

    const int t = threadIdx.x;
    const int w = t >> 6;
    const int lane = t & 63;
    const int o = w * 16 + (lane & 15); // owned output capsule
    const int cq = lane >> 4;           // c-quarter (0..3)
    const int c0 = cq * 8;
    const int n = blockIdx.x;
    const int bq = n / 36;
    const int sp = n - bq * 36;

    // ---- setup: vectorized index loads + table-driven gathers ----
    const int hc = o >> 1;
    const ushort8v sv8 = *(const ushort8v*)(sidx + sp * 512 + hc * 32 + c0);
    const uchar8v av8 = *(const uchar8v*)(aidx + sp * 32 + c0);
    const float* Sb = S + bq * 576;
    const float* Ab = A + bq * 36;
    f2 V2[8][2];
    float avr[8], r[8];
    const float* Wn = Wsum + sp * 4096;
#pragma unroll
    for (int cl = 0; cl < 8; ++cl) {
        int c = c0 + cl;
        float sv = Sb[sv8[cl]];
        float4 w4 = *(const float4*)(Wn + c * 128 + o * 4);
        V2[cl][0] = (f2){sv * w4.x, sv * w4.y};
        V2[cl][1] = (f2){sv * w4.z, sv * w4.w};
        avr[cl] = Ab[av8[cl]];
        r[cl] = 0.03125f;
    }
    const float bu16 = 16.0f * bu[o];
    const float ba_o = ba[o];
    f2 mu2[2], q2K[2];
    float aout = 0.f;
    const float lambdas[3] = {5.0e-4f, 9.75e-4f, 1.42625e-3f};

    for (int it = 0; it < 3; ++it) {
        // ---- ONE-PASS m-step: rs, S1=Σrp·V, S2=Σrp·V² share the rp·V product;
        //      all 9 cross-lane reduces independent ----
        float rp[8];
#pragma unroll
        for (int cl = 0; cl < 8; ++cl) rp[cl] = r[cl] * avr[cl] + EPSF;
        float rs = ((rp[0] + rp[1]) + (rp[2] + rp[3]))
                 + ((rp[4] + rp[5]) + (rp[6] + rp[7]));
        f2 S1[2], S2[2];
#pragma unroll
        for (int p = 0; p < 2; ++p) {
            f2 a0 = {0.f, 0.f}, a1 = {0.f, 0.f};
            f2 b0 = {0.f, 0.f}, b1 = {0.f, 0.f};
#pragma unroll
            for (int cl = 0; cl < 8; cl += 2) {
                f2 pv0 = rp[cl] * V2[cl][p];
                f2 pv1 = rp[cl + 1] * V2[cl + 1][p];
                a0 += pv0;
                a1 += pv1;
                b0 += pv0 * V2[cl][p];
                b1 += pv1 * V2[cl + 1][p];
            }
            S1[p] = a0 + a1;
            S2[p] = b0 + b1;
        }
        rs = reduce4(rs);
        S1[0].x = reduce4(S1[0].x); S1[0].y = reduce4(S1[0].y);
        S1[1].x = reduce4(S1[1].x); S1[1].y = reduce4(S1[1].y);
        S2[0].x = reduce4(S2[0].x); S2[0].y = reduce4(S2[0].y);
        S2[1].x = reduce4(S2[1].x); S2[1].y = reduce4(S2[1].y);
        float rinv = rcpf(rs);
        float L2;
        {
            f2 sgv[2];
#pragma unroll
            for (int p = 0; p < 2; ++p) {
                mu2[p] = S1[p] * rinv;
                f2 sg = S2[p] * rinv - mu2[p] * mu2[p];
                // clamp: cancellation can drive sg slightly negative in the
                // degenerate r-concentration limit (R5's NaN); both branches
                // converge to the same argmax behavior.
                sg.x = fmaxf(sg.x, 0.0f) + EPSF;
                sg.y = fmaxf(sg.y, 0.0f) + EPSF;
                sgv[p] = sg;
                q2K[p] = (f2){(2.0f * LOG2E_F) * rcpf(sg.x),
                              (2.0f * LOG2E_F) * rcpf(sg.y)};
            }
            L2 = log2f_hw((sgv[0].x * sgv[0].y) * (sgv[1].x * sgv[1].y));
        }
        float cost = (bu16 + LN2X2_F * L2) * rs;   // 2*L (natural) = 2*ln2*L2
        float z = lambdas[it] * (ba_o - cost);
        float e2z = exp2f_hw(-z * LOG2E_F);        // e^{-z}

        if (it < 2) {
            // base-2 log-sigmoid: la*K = -log2(1 + e^{-z})
            float laK = -log2f_hw(1.0f + e2z);
            float TK = laK - 2.0f * L2;            // logits in log2 units
#pragma unroll
            for (int cl = 0; cl < 8; ++cl) {
                f2 d0 = V2[cl][0] - mu2[0];
                f2 d1 = V2[cl][1] - mu2[1];
                f2 s2 = (d0 * d0) * q2K[0] + (d1 * d1) * q2K[1];
                lgb[(c0 + cl) * 33 + o] = TK - (s2.x + s2.y);
            }
            __syncthreads();
            // transposed softmax (base-2): 128 lanes, lane = (c-row, o-quarter)
            {
                int cT = t >> 2, q = t & 3;
                float* rowp = &lgb[cT * 33 + q * 8];
                float4 u0 = *(float4*)(rowp);
                float4 u1 = *(float4*)(rowp + 4);
                float m0 = fmaxf(fmaxf(u0.x, u0.y), fmaxf(u0.z, u0.w));
                float m1 = fmaxf(fmaxf(u1.x, u1.y), fmaxf(u1.z, u1.w));
                float m = fmaxf(m0, m1);
                m = fmaxf(m, dpp_xor1(m));
                m = fmaxf(m, dpp_xor2(m));
                u0.x = exp2f_hw(u0.x - m); u0.y = exp2f_hw(u0.y - m);
                u0.z = exp2f_hw(u0.z - m); u0.w = exp2f_hw(u0.w - m);
                u1.x = exp2f_hw(u1.x - m); u1.y = exp2f_hw(u1.y - m);
                u1.z = exp2f_hw(u1.z - m); u1.w = exp2f_hw(u1.w - m);
                float s0 = (u0.x + u0.y) + (u0.z + u0.w);
                float s1 = (u1.x + u1.y) + (u1.z + u1.w);
                float ssum = s0 + s1;
                ssum += dpp_xor1(ssum);
                ssum += dpp_xor2(ssum);
                float inv = rcpf(ssum);
                u0.x *= inv; u0.y *= inv; u0.z *= inv; u0.w *= inv;
                u1.x *= inv; u1.y *= inv; u1.z *= inv; u1.w *= inv;
                *(float4*)(rowp)     = u0;
                *(float4*)(rowp + 4) = u1;
            }
            __syncthreads();
#pragma unroll
            for (int cl = 0; cl < 8; ++cl)
                r[cl] = lgb[(c0 + cl) * 33 + o];
        } else {
            aout = rcpf(1.0f + e2z);
        }
    }

    // outputs: mu expanded to 16 k (k>>2 drops out); 4 cq-lanes hold identical
    // mu for their o — each writes one float4 quarter of the 16-k row.
    float4 val = {mu2[0].x, mu2[0].y, mu2[1].x, mu2[1].y};
    float4* po = (float4*)(out + n * 512 + o * 16);
    po[cq] = val;
    if (cq == 0) out[1179648 + n * 32 + o] = aout;
}

extern "C" void kernel_launch(void* const* d_in, const int* in_sizes, int n_in,
                              void* d_out, int out_size, void* d_ws, size_t ws_size,
                              hipStream_t stream) {
    const float* x = (const float*)d_in[0];
    const float* a = (const float*)d_in[1];
    const float* w = (const float*)d_in[2];
    const float* bu = (const float*)d_in[3];
    const float* ba = (const float*)d_in[4];
    float* out = (float*)d_out;

    float* S    = (float*)d_ws;                       // 36864 f
    float* A    = S + 36864;                          // 2304 f
    float* Wsum = A + 2304;                           // 147456 f
    unsigned short* sidx = (unsigned short*)(Wsum + 147456);  // 18432 u16
    unsigned char*  aidx = (unsigned char*)(sidx + 18432);    // 1152 u8

    pre_kernel<<<1088 + 576 + 77, 256, 0, stream>>>(x, a, w, S, A, Wsum, sidx, aidx);
    em_kernel<<<2304, 128, 0, stream>>>(bu, ba, S, A, Wsum, sidx, aidx, out);
}